// Round 1
// baseline (410.900 us; speedup 1.0000x reference)
//
#include <hip/hip_runtime.h>
#include <hip/hip_bf16.h>

#define NEG (-1e30f)
#define M_ROWS 8000   // B*T = 16*500
#define N_COLS 5000   // V
#define K_DIM  256    // D
#define T_LEN  500
#define B_SZ   16
#define L_LAB  50
#define LDS_STR 72    // 64 + 8 pad (bf16/f16 elems) to spread LDS banks

typedef _Float16 half8  __attribute__((ext_vector_type(8)));
typedef _Float16 half4v __attribute__((ext_vector_type(4)));
typedef float    floatx4 __attribute__((ext_vector_type(4)));

__device__ __forceinline__ float laexp(float a, float b) {
  float m = fmaxf(a, b);
  float d = fminf(a, b) - m;          // <= 0; both NEG -> d = 0 -> m + log(2), matches jnp
  return m + __logf(1.0f + __expf(d));
}

// ---------------- zero the scalar output (d_out poisoned 0xAA before timed runs) ----
__global__ void k_zero(float* out) { out[0] = 0.0f; }

// ---------------- fp32 -> fp16 convert, 4 elems/thread ------------------------------
__global__ void k_f2h(const float* __restrict__ in, _Float16* __restrict__ out, int n4) {
  int i = blockIdx.x * blockDim.x + threadIdx.x;
  if (i < n4) {
    float4 v = ((const float4*)in)[i];
    half4v o = {(_Float16)v.x, (_Float16)v.y, (_Float16)v.z, (_Float16)v.w};
    ((half4v*)out)[i] = o;
  }
}

// ---------------- MFMA GEMM (M=8000,N=5000,K=256) with fused per-64col lse partials --
// A = enc f16 [8000][256] row-major, B = W f16 [5000][256] ([n][k], i.e. B^T form).
// No C write: epilogue reduces each row over the 128-col tile into (max, sumexp)
// partials at 64-col granularity -> pmax/psum [8000][80].
__global__ __launch_bounds__(256) void k_gemm_lse(
    const _Float16* __restrict__ A, const _Float16* __restrict__ Bm,
    const float* __restrict__ bias, float* __restrict__ pmax, float* __restrict__ psum) {
  __shared__ _Float16 As[128 * LDS_STR];
  __shared__ _Float16 Bs[128 * LDS_STR];

  const int tid = threadIdx.x;
  const int lane = tid & 63;
  const int wid = tid >> 6;
  const int wave_m = wid & 1, wave_n = wid >> 1;   // 2x2 waves of 64x64
  const int l15 = lane & 15, quad = lane >> 4;
  const int m0 = blockIdx.y * 128, n0 = blockIdx.x * 128;

  floatx4 acc[4][4];
  floatx4 zz = {0.f, 0.f, 0.f, 0.f};
  #pragma unroll
  for (int mi = 0; mi < 4; ++mi)
    #pragma unroll
    for (int ni = 0; ni < 4; ++ni) acc[mi][ni] = zz;

  for (int kk = 0; kk < K_DIM; kk += 64) {
    // stage 128x64 f16 tiles of A and B via registers (16B per thread per round)
    #pragma unroll
    for (int r = 0; r < 4; ++r) {
      int flat = r * 256 + tid;            // 0..1023
      int row = flat >> 3, c8 = flat & 7;  // 8 x int4 per 64-elem row
      int ga = m0 + row; if (ga > M_ROWS - 1) ga = M_ROWS - 1;
      int4 av = *(const int4*)(A + (size_t)ga * K_DIM + kk + c8 * 8);
      *(int4*)(As + row * LDS_STR + c8 * 8) = av;
      int gb = n0 + row; if (gb > N_COLS - 1) gb = N_COLS - 1;
      int4 bv = *(const int4*)(Bm + (size_t)gb * K_DIM + kk + c8 * 8);
      *(int4*)(Bs + row * LDS_STR + c8 * 8) = bv;
    }
    __syncthreads();
    #pragma unroll
    for (int ko = 0; ko < 64; ko += 32) {
      half8 af[4], bf[4];
      #pragma unroll
      for (int mi = 0; mi < 4; ++mi)
        af[mi] = *(const half8*)(As + (wave_m * 64 + mi * 16 + l15) * LDS_STR + ko + quad * 8);
      #pragma unroll
      for (int ni = 0; ni < 4; ++ni)
        bf[ni] = *(const half8*)(Bs + (wave_n * 64 + ni * 16 + l15) * LDS_STR + ko + quad * 8);
      #pragma unroll
      for (int mi = 0; mi < 4; ++mi)
        #pragma unroll
        for (int ni = 0; ni < 4; ++ni)
          acc[mi][ni] = __builtin_amdgcn_mfma_f32_16x16x32_f16(af[mi], bf[ni], acc[mi][ni], 0, 0, 0);
    }
    __syncthreads();
  }

  // epilogue: add bias, mask cols >= V, reduce row-wise over this wave's 64 cols.
  // C/D layout: col = lane&15, row = quad*4 + reg  (dtype-independent, m89/m101)
  float bvv[4]; bool cok[4];
  #pragma unroll
  for (int ni = 0; ni < 4; ++ni) {
    int col = n0 + wave_n * 64 + ni * 16 + l15;
    cok[ni] = (col < N_COLS);
    bvv[ni] = cok[ni] ? bias[col] : 0.f;
  }
  const int cchunk = blockIdx.x * 2 + wave_n;  // 64-col chunk id, 0..79
  #pragma unroll
  for (int mi = 0; mi < 4; ++mi) {
    #pragma unroll
    for (int r = 0; r < 4; ++r) {
      int grow = m0 + wave_m * 64 + mi * 16 + quad * 4 + r;
      float v0 = cok[0] ? acc[mi][0][r] + bvv[0] : NEG;
      float v1 = cok[1] ? acc[mi][1][r] + bvv[1] : NEG;
      float v2 = cok[2] ? acc[mi][2][r] + bvv[2] : NEG;
      float v3 = cok[3] ? acc[mi][3][r] + bvv[3] : NEG;
      float mx = fmaxf(fmaxf(v0, v1), fmaxf(v2, v3));
      #pragma unroll
      for (int d = 1; d < 16; d <<= 1) mx = fmaxf(mx, __shfl_xor(mx, d));
      float se = __expf(v0 - mx) + __expf(v1 - mx) + __expf(v2 - mx) + __expf(v3 - mx);
      #pragma unroll
      for (int d = 1; d < 16; d <<= 1) se += __shfl_xor(se, d);
      if (l15 == 0 && grow < M_ROWS) {
        pmax[(size_t)grow * 80 + cchunk] = mx;
        psum[(size_t)grow * 80 + cchunk] = se;
      }
    }
  }
}

// ---------------- combine 80 per-chunk partials -> lse[row] --------------------------
__global__ void k_lse(const float* __restrict__ pmax, const float* __restrict__ psum,
                      float* __restrict__ lse) {
  int row = blockIdx.x, lane = threadIdx.x;
  float m0 = pmax[(size_t)row * 80 + lane];
  float s0 = psum[(size_t)row * 80 + lane];
  float m1 = NEG, s1 = 0.f;
  if (lane < 16) { m1 = pmax[(size_t)row * 80 + 64 + lane]; s1 = psum[(size_t)row * 80 + 64 + lane]; }
  float m = fmaxf(m0, m1);
  #pragma unroll
  for (int d = 1; d < 64; d <<= 1) m = fmaxf(m, __shfl_xor(m, d));
  float s = s0 * __expf(m0 - m) + s1 * __expf(m1 - m);
  #pragma unroll
  for (int d = 1; d < 64; d <<= 1) s += __shfl_xor(s, d);
  if (lane == 0) lse[row] = m + __logf(s);
}

// ---------------- gather raw label logits (fp32-exact): lg[row][j], j=0 blank, 1..50 = y
// one block = 4 consecutive rows (same b since 500 % 4 == 0), 64 lanes = k-chunks.
__global__ void k_gather(const float* __restrict__ enc, const float* __restrict__ W,
                         const float* __restrict__ bias, const int* __restrict__ y,
                         float* __restrict__ lg) {
  int row0 = blockIdx.x * 4;
  int lane = threadIdx.x;
  int b = row0 / T_LEN;
  float4 e0 = ((const float4*)(enc + (size_t)(row0 + 0) * 256))[lane];
  float4 e1 = ((const float4*)(enc + (size_t)(row0 + 1) * 256))[lane];
  float4 e2 = ((const float4*)(enc + (size_t)(row0 + 2) * 256))[lane];
  float4 e3 = ((const float4*)(enc + (size_t)(row0 + 3) * 256))[lane];
  if (lane >= 51) {  // pad unused label slots with NEG for the DP kernel
    lg[(size_t)(row0 + 0) * 64 + lane] = NEG;
    lg[(size_t)(row0 + 1) * 64 + lane] = NEG;
    lg[(size_t)(row0 + 2) * 64 + lane] = NEG;
    lg[(size_t)(row0 + 3) * 64 + lane] = NEG;
  }
  for (int j = 0; j < 51; ++j) {
    int v = (j == 0) ? 0 : y[b * L_LAB + j - 1];
    float4 w = ((const float4*)(W + (size_t)v * 256))[lane];  // coalesced full row
    float p0 = e0.x * w.x + e0.y * w.y + e0.z * w.z + e0.w * w.w;
    float p1 = e1.x * w.x + e1.y * w.y + e1.z * w.z + e1.w * w.w;
    float p2 = e2.x * w.x + e2.y * w.y + e2.z * w.z + e2.w * w.w;
    float p3 = e3.x * w.x + e3.y * w.y + e3.z * w.z + e3.w * w.w;
    #pragma unroll
    for (int d = 1; d < 64; d <<= 1) {
      p0 += __shfl_xor(p0, d);
      p1 += __shfl_xor(p1, d);
      p2 += __shfl_xor(p2, d);
      p3 += __shfl_xor(p3, d);
    }
    if (lane == 0) {
      float bb = bias[v];
      lg[(size_t)(row0 + 0) * 64 + j] = p0 + bb;
      lg[(size_t)(row0 + 1) * 64 + j] = p1 + bb;
      lg[(size_t)(row0 + 2) * 64 + j] = p2 + bb;
      lg[(size_t)(row0 + 3) * 64 + j] = p3 + bb;
    }
  }
}

// ---------------- CTC forward DP, one wave per batch element -------------------------
// Raw-logit DP: -lse[t] is uniform over states at step t, so defer it:
// neg_logp = sum_t lse[t] - logaddexp(alphaRaw[2yl], alphaRaw[2yl-1]).
// lane i holds states s=2i (blank, label slot 0) and s=2i+1 (label slot i+1).
__global__ void k_dp(const float* __restrict__ lg, const float* __restrict__ lse,
                     const int* __restrict__ enc_lens, const int* __restrict__ y,
                     const int* __restrict__ y_lens, float* __restrict__ out) {
  int b = blockIdx.x, i = threadIdx.x;
  int Tb = enc_lens[b], yl = y_lens[b];

  float sl = 0.f;
  for (int t = i; t < Tb; t += 64) sl += lse[b * T_LEN + t];
  #pragma unroll
  for (int d = 1; d < 64; d <<= 1) sl += __shfl_xor(sl, d);

  bool skip1 = (i >= 1 && i <= 49) && (y[b * L_LAB + i] != y[b * L_LAB + i - 1]);
  bool v0 = (i <= 50), v1 = (i <= 49);
  const float* lgb = lg + (size_t)b * T_LEN * 64;

  float a0 = (i == 0) ? lgb[0] : NEG;  // alpha[s=0] = lp_ext[0,0]
  float a1 = (i == 0) ? lgb[1] : NEG;  // alpha[s=1] = lp_ext[0,1]

  for (int t = 1; t < Tb; ++t) {
    const float* rr = lgb + (size_t)t * 64;
    float l0 = v0 ? rr[0] : NEG;        // blank logit (broadcast)
    float l1 = v1 ? rr[i + 1] : NEG;    // label-i logit (coalesced)
    float p1 = __shfl_up(a1, 1);        // alpha[2i-1]
    if (i == 0) p1 = NEG;
    float na0 = laexp(a0, p1) + l0;                       // even state: no skip ever
    float mm = laexp(a1, a0);                             // odd state: self + below
    float third = skip1 ? p1 : NEG;                       // + skip path alpha[2i-1]
    float na1 = laexp(mm, third) + l1;
    a0 = na0; a1 = na1;
  }
  float ea = __shfl(a0, yl);       // s = 2*yl   (even -> a0 of lane yl)
  float eb = __shfl(a1, yl - 1);   // s = 2*yl-1 (odd  -> a1 of lane yl-1)
  if (i == 0) {
    float fin = laexp(ea, eb);
    atomicAdd(out, (sl - fin) * (1.0f / (float)B_SZ));
  }
}

extern "C" void kernel_launch(void* const* d_in, const int* in_sizes, int n_in,
                              void* d_out, int out_size, void* d_ws, size_t ws_size,
                              hipStream_t stream) {
  (void)in_sizes; (void)n_in; (void)out_size; (void)ws_size;
  const float* enc      = (const float*)d_in[0];   // [16][500][256]
  const int*   enc_lens = (const int*)d_in[1];     // [16]
  const int*   y        = (const int*)d_in[2];     // [16][50]
  const int*   y_lens   = (const int*)d_in[3];     // [16]
  const float* W        = (const float*)d_in[4];   // [5000][256]
  const float* bias     = (const float*)d_in[5];   // [5000]
  float* out = (float*)d_out;

  char* ws = (char*)d_ws;
  _Float16* ench = (_Float16*)(ws + 0);            // 4,096,000 B
  _Float16* wh   = (_Float16*)(ws + 4096000);      // 2,560,000 B
  float* pmax    = (float*)(ws + 6656000);         // 2,560,000 B
  float* psum    = (float*)(ws + 9216000);         // 2,560,000 B
  float* lse     = (float*)(ws + 11776000);        //    32,000 B
  float* lg      = (float*)(ws + 11808000);        // 2,048,000 B   (total ~13.9 MB)

  k_zero<<<1, 1, 0, stream>>>(out);
  k_f2h<<<(512000 + 255) / 256, 256, 0, stream>>>(enc, ench, 512000);  // 2,048,000/4
  k_f2h<<<(320000 + 255) / 256, 256, 0, stream>>>(W, wh, 320000);      // 1,280,000/4
  k_gemm_lse<<<dim3(40, 63), 256, 0, stream>>>(ench, wh, bias, pmax, psum);
  k_gather<<<2000, 64, 0, stream>>>(enc, W, bias, y, lg);
  k_lse<<<8000, 64, 0, stream>>>(pmax, psum, lse);
  k_dp<<<16, 64, 0, stream>>>(lg, lse, enc_lens, y, y_lens, out);
}

// Round 2
// 244.767 us; speedup vs baseline: 1.6787x; 1.6787x over previous
//
#include <hip/hip_runtime.h>
#include <hip/hip_bf16.h>

#define NEG (-1e30f)
#define M_ROWS 8000   // B*T = 16*500
#define N_COLS 5000   // V
#define K_DIM  256    // D
#define T_LEN  500
#define T_PAD  512    // lgT inner stride (t), padded
#define B_SZ   16
#define L_LAB  50
#define LDS_STR 72    // 64 + 8 pad (f16 elems)

typedef _Float16 half8  __attribute__((ext_vector_type(8)));
typedef _Float16 half4v __attribute__((ext_vector_type(4)));
typedef float    floatx4 __attribute__((ext_vector_type(4)));

// ---------------- zero the scalar output ------------------------------------------
__global__ void k_zero(float* out) { out[0] = 0.0f; }

// ---------------- fp32 -> fp16 convert, 4 elems/thread ----------------------------
__global__ void k_f2h(const float* __restrict__ in, _Float16* __restrict__ out, int n4) {
  int i = blockIdx.x * blockDim.x + threadIdx.x;
  if (i < n4) {
    float4 v = ((const float4*)in)[i];
    half4v o = {(_Float16)v.x, (_Float16)v.y, (_Float16)v.z, (_Float16)v.w};
    ((half4v*)out)[i] = o;
  }
}

// ---------------- MFMA GEMM with fused per-64col lse partials ---------------------
__global__ __launch_bounds__(256) void k_gemm_lse(
    const _Float16* __restrict__ A, const _Float16* __restrict__ Bm,
    const float* __restrict__ bias, float* __restrict__ pmax, float* __restrict__ psum) {
  __shared__ _Float16 As[128 * LDS_STR];
  __shared__ _Float16 Bs[128 * LDS_STR];

  const int tid = threadIdx.x;
  const int lane = tid & 63;
  const int wid = tid >> 6;
  const int wave_m = wid & 1, wave_n = wid >> 1;   // 2x2 waves of 64x64
  const int l15 = lane & 15, quad = lane >> 4;
  const int m0 = blockIdx.y * 128, n0 = blockIdx.x * 128;

  floatx4 acc[4][4];
  floatx4 zz = {0.f, 0.f, 0.f, 0.f};
  #pragma unroll
  for (int mi = 0; mi < 4; ++mi)
    #pragma unroll
    for (int ni = 0; ni < 4; ++ni) acc[mi][ni] = zz;

  for (int kk = 0; kk < K_DIM; kk += 64) {
    #pragma unroll
    for (int r = 0; r < 4; ++r) {
      int flat = r * 256 + tid;
      int row = flat >> 3, c8 = flat & 7;
      int ga = m0 + row; if (ga > M_ROWS - 1) ga = M_ROWS - 1;
      int4 av = *(const int4*)(A + (size_t)ga * K_DIM + kk + c8 * 8);
      *(int4*)(As + row * LDS_STR + c8 * 8) = av;
      int gb = n0 + row; if (gb > N_COLS - 1) gb = N_COLS - 1;
      int4 bv = *(const int4*)(Bm + (size_t)gb * K_DIM + kk + c8 * 8);
      *(int4*)(Bs + row * LDS_STR + c8 * 8) = bv;
    }
    __syncthreads();
    #pragma unroll
    for (int ko = 0; ko < 64; ko += 32) {
      half8 af[4], bf[4];
      #pragma unroll
      for (int mi = 0; mi < 4; ++mi)
        af[mi] = *(const half8*)(As + (wave_m * 64 + mi * 16 + l15) * LDS_STR + ko + quad * 8);
      #pragma unroll
      for (int ni = 0; ni < 4; ++ni)
        bf[ni] = *(const half8*)(Bs + (wave_n * 64 + ni * 16 + l15) * LDS_STR + ko + quad * 8);
      #pragma unroll
      for (int mi = 0; mi < 4; ++mi)
        #pragma unroll
        for (int ni = 0; ni < 4; ++ni)
          acc[mi][ni] = __builtin_amdgcn_mfma_f32_16x16x32_f16(af[mi], bf[ni], acc[mi][ni], 0, 0, 0);
    }
    __syncthreads();
  }

  float bvv[4]; bool cok[4];
  #pragma unroll
  for (int ni = 0; ni < 4; ++ni) {
    int col = n0 + wave_n * 64 + ni * 16 + l15;
    cok[ni] = (col < N_COLS);
    bvv[ni] = cok[ni] ? bias[col] : 0.f;
  }
  const int cchunk = blockIdx.x * 2 + wave_n;
  #pragma unroll
  for (int mi = 0; mi < 4; ++mi) {
    #pragma unroll
    for (int r = 0; r < 4; ++r) {
      int grow = m0 + wave_m * 64 + mi * 16 + quad * 4 + r;
      float v0 = cok[0] ? acc[mi][0][r] + bvv[0] : NEG;
      float v1 = cok[1] ? acc[mi][1][r] + bvv[1] : NEG;
      float v2 = cok[2] ? acc[mi][2][r] + bvv[2] : NEG;
      float v3 = cok[3] ? acc[mi][3][r] + bvv[3] : NEG;
      float mx = fmaxf(fmaxf(v0, v1), fmaxf(v2, v3));
      #pragma unroll
      for (int d = 1; d < 16; d <<= 1) mx = fmaxf(mx, __shfl_xor(mx, d));
      float se = __expf(v0 - mx) + __expf(v1 - mx) + __expf(v2 - mx) + __expf(v3 - mx);
      #pragma unroll
      for (int d = 1; d < 16; d <<= 1) se += __shfl_xor(se, d);
      if (l15 == 0 && grow < M_ROWS) {
        pmax[(size_t)grow * 80 + cchunk] = mx;
        psum[(size_t)grow * 80 + cchunk] = se;
      }
    }
  }
}

// ---------------- combine 80 per-chunk partials -> lse[row] -----------------------
__global__ void k_lse(const float* __restrict__ pmax, const float* __restrict__ psum,
                      float* __restrict__ lse) {
  int row = blockIdx.x, lane = threadIdx.x;
  float m0 = pmax[(size_t)row * 80 + lane];
  float s0 = psum[(size_t)row * 80 + lane];
  float m1 = NEG, s1 = 0.f;
  if (lane < 16) { m1 = pmax[(size_t)row * 80 + 64 + lane]; s1 = psum[(size_t)row * 80 + 64 + lane]; }
  float m = fmaxf(m0, m1);
  #pragma unroll
  for (int d = 1; d < 64; d <<= 1) m = fmaxf(m, __shfl_xor(m, d));
  float s = s0 * __expf(m0 - m) + s1 * __expf(m1 - m);
  #pragma unroll
  for (int d = 1; d < 64; d <<= 1) s += __shfl_xor(s, d);
  if (lane == 0) lse[row] = m + __logf(s);
}

// ---------------- gather raw label logits, TRANSPOSED: lgT[b][j][t] ---------------
// one block = 4 consecutive rows (same b, t0..t0+3), 64 lanes = k-chunks.
__global__ void k_gather(const float* __restrict__ enc, const float* __restrict__ W,
                         const float* __restrict__ bias, const int* __restrict__ y,
                         float* __restrict__ lgT) {
  int row0 = blockIdx.x * 4;
  int lane = threadIdx.x;
  int b = row0 / T_LEN;
  int t0 = row0 - b * T_LEN;
  float4 e0 = ((const float4*)(enc + (size_t)(row0 + 0) * 256))[lane];
  float4 e1 = ((const float4*)(enc + (size_t)(row0 + 1) * 256))[lane];
  float4 e2 = ((const float4*)(enc + (size_t)(row0 + 2) * 256))[lane];
  float4 e3 = ((const float4*)(enc + (size_t)(row0 + 3) * 256))[lane];
  for (int j = 0; j < 51; ++j) {
    int v = (j == 0) ? 0 : y[b * L_LAB + j - 1];
    float4 w = ((const float4*)(W + (size_t)v * 256))[lane];
    float p0 = e0.x * w.x + e0.y * w.y + e0.z * w.z + e0.w * w.w;
    float p1 = e1.x * w.x + e1.y * w.y + e1.z * w.z + e1.w * w.w;
    float p2 = e2.x * w.x + e2.y * w.y + e2.z * w.z + e2.w * w.w;
    float p3 = e3.x * w.x + e3.y * w.y + e3.z * w.z + e3.w * w.w;
    #pragma unroll
    for (int d = 1; d < 64; d <<= 1) {
      p0 += __shfl_xor(p0, d);
      p1 += __shfl_xor(p1, d);
      p2 += __shfl_xor(p2, d);
      p3 += __shfl_xor(p3, d);
    }
    if (lane == 0) {
      float bb = bias[v];
      float4 o = {p0 + bb, p1 + bb, p2 + bb, p3 + bb};
      *(float4*)(lgT + (size_t)(b * 64 + j) * T_PAD + t0) = o;
    }
  }
}

// ---------------- cross-lane shift-by-1 via DPP wave_shr:1 ------------------------
__device__ __forceinline__ float wave_shr1(float x, float fill) {
#if defined(__has_builtin)
#if __has_builtin(__builtin_amdgcn_update_dpp)
  int r = __builtin_amdgcn_update_dpp(__float_as_int(fill), __float_as_int(x),
                                      0x138 /*wave_shr:1*/, 0xf, 0xf, false);
  return __int_as_float(r);
#else
  return __shfl_up(x, 1);
#endif
#else
  return __shfl_up(x, 1);
#endif
}

// ---------------- CTC forward DP, one wave per batch element ----------------------
// Raw-logit DP with deferred -lse; lane i holds states s=2i and s=2i+1.
// lgT layout: [b][j][t], j=0 blank, j=1..50 labels, t padded to 512. float4 = 4 t's.
__global__ void k_dp(const float* __restrict__ lgT, const float* __restrict__ lse,
                     const int* __restrict__ enc_lens, const int* __restrict__ y,
                     const int* __restrict__ y_lens, float* __restrict__ out) {
  const int b = blockIdx.x, i = threadIdx.x;
  const int Tb = enc_lens[b], yl = y_lens[b];

  const int jj = (i + 1 < 64) ? (i + 1) : 63;        // clamp; lanes>=50 masked anyway
  const float* bl = lgT + (size_t)(b * 64) * T_PAD;       // blank row (broadcast)
  const float* ow = lgT + (size_t)(b * 64 + jj) * T_PAD;  // own label row
  const bool v1 = (i <= 49);
  const bool lane0 = (i == 0);
  const bool skip1 = (i >= 1 && i <= 49) && (y[b * L_LAB + i] != y[b * L_LAB + i - 1]);

  // 4-deep prefetch of t-groups (A:0-3, B:4-7, C:8-11, D:12-15), issued before the
  // lse-sum reduction so global latency overlaps it.
  float4 A0 = *(const float4*)(bl + 0),  A1 = *(const float4*)(ow + 0);
  float4 B0 = *(const float4*)(bl + 4),  B1 = *(const float4*)(ow + 4);
  float4 C0 = *(const float4*)(bl + 8),  C1 = *(const float4*)(ow + 8);
  float4 D0 = *(const float4*)(bl + 12), D1 = *(const float4*)(ow + 12);

  float sl = 0.f;
  for (int t = i; t < Tb; t += 64) sl += lse[b * T_LEN + t];
  #pragma unroll
  for (int d = 1; d < 64; d <<= 1) sl += __shfl_xor(sl, d);

  const float4 n4 = {NEG, NEG, NEG, NEG};
  if (!v1) { A1 = n4; B1 = n4; C1 = n4; D1 = n4; }

  float a0 = lane0 ? A0.x : NEG;   // alpha[s=0] = blank logit at t=0
  float a1 = lane0 ? A1.x : NEG;   // alpha[s=1] = label-1 logit at t=0 (lane 0)

  auto step = [&](float l0, float l1) {
    float p1 = wave_shr1(a1, NEG);           // alpha[2i-1] from lane i-1
    p1 = lane0 ? NEG : p1;                   // guard regardless of bound_ctrl semantics
    float th = skip1 ? p1 : NEG;
    float m0 = fmaxf(a0, p1);
    float na0 = m0 + __logf(__expf(a0 - m0) + __expf(p1 - m0)) + l0;
    float m1 = fmaxf(fmaxf(a1, a0), th);     // v_max3
    float na1 = m1 + __logf(__expf(a1 - m1) + __expf(a0 - m1) + __expf(th - m1)) + l1;
    a0 = na0; a1 = na1;
  };

  // t = 1..3 from group A
  step(A0.y, A1.y);
  step(A0.z, A1.z);
  step(A0.w, A1.w);

  float4 c0 = B0, c1 = B1, n0 = C0, n1 = C1, nn0 = D0, nn1 = D1;
  int t = 4;
  while (t + 4 <= Tb) {
    // prefetch group t+12 (max addr 508+3 = 511 < 512, always in-bounds)
    float4 p0 = *(const float4*)(bl + t + 12);
    float4 p1v = *(const float4*)(ow + t + 12);
    if (!v1) p1v = n4;
    step(c0.x, c1.x);
    step(c0.y, c1.y);
    step(c0.z, c1.z);
    step(c0.w, c1.w);
    c0 = n0; c1 = n1; n0 = nn0; n1 = nn1; nn0 = p0; nn1 = p1v;
    t += 4;
  }
  if (t < Tb) { step(c0.x, c1.x); ++t; }
  if (t < Tb) { step(c0.y, c1.y); ++t; }
  if (t < Tb) { step(c0.z, c1.z); ++t; }

  float ea = __shfl(a0, yl);       // s = 2*yl
  float eb = __shfl(a1, yl - 1);   // s = 2*yl-1
  if (lane0) {
    float m = fmaxf(ea, eb);
    float fin = m + __logf(__expf(ea - m) + __expf(eb - m));
    atomicAdd(out, (sl - fin) * (1.0f / (float)B_SZ));
  }
}

extern "C" void kernel_launch(void* const* d_in, const int* in_sizes, int n_in,
                              void* d_out, int out_size, void* d_ws, size_t ws_size,
                              hipStream_t stream) {
  (void)in_sizes; (void)n_in; (void)out_size; (void)ws_size;
  const float* enc      = (const float*)d_in[0];   // [16][500][256]
  const int*   enc_lens = (const int*)d_in[1];     // [16]
  const int*   y        = (const int*)d_in[2];     // [16][50]
  const int*   y_lens   = (const int*)d_in[3];     // [16]
  const float* W        = (const float*)d_in[4];   // [5000][256]
  const float* bias     = (const float*)d_in[5];   // [5000]
  float* out = (float*)d_out;

  char* ws = (char*)d_ws;
  _Float16* ench = (_Float16*)(ws + 0);            // 4,096,000 B
  _Float16* wh   = (_Float16*)(ws + 4096000);      // 2,560,000 B
  float* pmax    = (float*)(ws + 6656000);         // 2,560,000 B
  float* psum    = (float*)(ws + 9216000);         // 2,560,000 B
  float* lse     = (float*)(ws + 11776000);        //    32,000 B
  // lgT [16][64][512] f32 = 2,097,152 B — aliases ench (consumed by k_gemm_lse,
  // which is stream-ordered before k_gather writes it).
  float* lgT     = (float*)(ws + 0);

  k_zero<<<1, 1, 0, stream>>>(out);
  k_f2h<<<(512000 + 255) / 256, 256, 0, stream>>>(enc, ench, 512000);
  k_f2h<<<(320000 + 255) / 256, 256, 0, stream>>>(W, wh, 320000);
  k_gemm_lse<<<dim3(40, 63), 256, 0, stream>>>(ench, wh, bias, pmax, psum);
  k_gather<<<2000, 64, 0, stream>>>(enc, W, bias, y, lgT);   // overwrites ench region
  k_lse<<<8000, 64, 0, stream>>>(pmax, psum, lse);
  k_dp<<<16, 64, 0, stream>>>(lgT, lse, enc_lens, y, y_lens, out);
}

// Round 3
// 212.163 us; speedup vs baseline: 1.9367x; 1.1537x over previous
//
#include <hip/hip_runtime.h>
#include <hip/hip_bf16.h>

#define NEG (-1e30f)
#define M_ROWS 8000   // B*T = 16*500
#define N_COLS 5000   // V
#define K_DIM  256    // D
#define T_LEN  500
#define T_PAD  512    // lgT inner stride (t), padded
#define B_SZ   16
#define L_LAB  50
#define LDS_STR 72    // 64 + 8 pad (f16 elems)
#define DP_STR  516   // LDS row stride (dwords) in k_dp: (4*row+t)%32 even banks
#define LOG2E   1.4426950408889634f
#define LN2     0.6931471805599453f

typedef _Float16 half8  __attribute__((ext_vector_type(8)));
typedef _Float16 half4v __attribute__((ext_vector_type(4)));
typedef float    floatx4 __attribute__((ext_vector_type(4)));

__device__ __forceinline__ float fexp2(float x) {
#if defined(__has_builtin)
#if __has_builtin(__builtin_amdgcn_exp2f)
  return __builtin_amdgcn_exp2f(x);
#else
  return __expf(x * LN2);
#endif
#else
  return __expf(x * LN2);
#endif
}
__device__ __forceinline__ float flog2(float x) {
#if defined(__has_builtin)
#if __has_builtin(__builtin_amdgcn_logf)
  return __builtin_amdgcn_logf(x);   // raw v_log_f32 = log2
#else
  return __logf(x) * LOG2E;
#endif
#else
  return __logf(x) * LOG2E;
#endif
}

// ---------------- fp32 -> fp16 convert, 4 elems/thread; optional out-zeroing ------
__global__ void k_f2h(const float* __restrict__ in, _Float16* __restrict__ out, int n4,
                      float* z) {
  int i = blockIdx.x * blockDim.x + threadIdx.x;
  if (z && i == 0) z[0] = 0.0f;
  if (i < n4) {
    float4 v = ((const float4*)in)[i];
    half4v o = {(_Float16)v.x, (_Float16)v.y, (_Float16)v.z, (_Float16)v.w};
    ((half4v*)out)[i] = o;
  }
}

// ---------------- MFMA GEMM with fused per-64col lse partials ---------------------
__global__ __launch_bounds__(256) void k_gemm_lse(
    const _Float16* __restrict__ A, const _Float16* __restrict__ Bm,
    const float* __restrict__ bias, float* __restrict__ pmax, float* __restrict__ psum) {
  __shared__ _Float16 As[128 * LDS_STR];
  __shared__ _Float16 Bs[128 * LDS_STR];

  const int tid = threadIdx.x;
  const int lane = tid & 63;
  const int wid = tid >> 6;
  const int wave_m = wid & 1, wave_n = wid >> 1;   // 2x2 waves of 64x64
  const int l15 = lane & 15, quad = lane >> 4;
  const int m0 = blockIdx.y * 128, n0 = blockIdx.x * 128;

  floatx4 acc[4][4];
  floatx4 zz = {0.f, 0.f, 0.f, 0.f};
  #pragma unroll
  for (int mi = 0; mi < 4; ++mi)
    #pragma unroll
    for (int ni = 0; ni < 4; ++ni) acc[mi][ni] = zz;

  for (int kk = 0; kk < K_DIM; kk += 64) {
    #pragma unroll
    for (int r = 0; r < 4; ++r) {
      int flat = r * 256 + tid;
      int row = flat >> 3, c8 = flat & 7;
      int ga = m0 + row; if (ga > M_ROWS - 1) ga = M_ROWS - 1;
      int4 av = *(const int4*)(A + (size_t)ga * K_DIM + kk + c8 * 8);
      *(int4*)(As + row * LDS_STR + c8 * 8) = av;
      int gb = n0 + row; if (gb > N_COLS - 1) gb = N_COLS - 1;
      int4 bv = *(const int4*)(Bm + (size_t)gb * K_DIM + kk + c8 * 8);
      *(int4*)(Bs + row * LDS_STR + c8 * 8) = bv;
    }
    __syncthreads();
    #pragma unroll
    for (int ko = 0; ko < 64; ko += 32) {
      half8 af[4], bf[4];
      #pragma unroll
      for (int mi = 0; mi < 4; ++mi)
        af[mi] = *(const half8*)(As + (wave_m * 64 + mi * 16 + l15) * LDS_STR + ko + quad * 8);
      #pragma unroll
      for (int ni = 0; ni < 4; ++ni)
        bf[ni] = *(const half8*)(Bs + (wave_n * 64 + ni * 16 + l15) * LDS_STR + ko + quad * 8);
      #pragma unroll
      for (int mi = 0; mi < 4; ++mi)
        #pragma unroll
        for (int ni = 0; ni < 4; ++ni)
          acc[mi][ni] = __builtin_amdgcn_mfma_f32_16x16x32_f16(af[mi], bf[ni], acc[mi][ni], 0, 0, 0);
    }
    __syncthreads();
  }

  float bvv[4]; bool cok[4];
  #pragma unroll
  for (int ni = 0; ni < 4; ++ni) {
    int col = n0 + wave_n * 64 + ni * 16 + l15;
    cok[ni] = (col < N_COLS);
    bvv[ni] = cok[ni] ? bias[col] : 0.f;
  }
  const int cchunk = blockIdx.x * 2 + wave_n;
  #pragma unroll
  for (int mi = 0; mi < 4; ++mi) {
    #pragma unroll
    for (int r = 0; r < 4; ++r) {
      int grow = m0 + wave_m * 64 + mi * 16 + quad * 4 + r;
      float v0 = cok[0] ? acc[mi][0][r] + bvv[0] : NEG;
      float v1 = cok[1] ? acc[mi][1][r] + bvv[1] : NEG;
      float v2 = cok[2] ? acc[mi][2][r] + bvv[2] : NEG;
      float v3 = cok[3] ? acc[mi][3][r] + bvv[3] : NEG;
      float mx = fmaxf(fmaxf(v0, v1), fmaxf(v2, v3));
      #pragma unroll
      for (int d = 1; d < 16; d <<= 1) mx = fmaxf(mx, __shfl_xor(mx, d));
      float se = __expf(v0 - mx) + __expf(v1 - mx) + __expf(v2 - mx) + __expf(v3 - mx);
      #pragma unroll
      for (int d = 1; d < 16; d <<= 1) se += __shfl_xor(se, d);
      if (l15 == 0 && grow < M_ROWS) {
        pmax[(size_t)grow * 80 + cchunk] = mx;
        psum[(size_t)grow * 80 + cchunk] = se;
      }
    }
  }
}

// ---------------- combine 80 per-chunk partials -> lse[row] -----------------------
__global__ void k_lse(const float* __restrict__ pmax, const float* __restrict__ psum,
                      float* __restrict__ lse) {
  int row = blockIdx.x, lane = threadIdx.x;
  float m0 = pmax[(size_t)row * 80 + lane];
  float s0 = psum[(size_t)row * 80 + lane];
  float m1 = NEG, s1 = 0.f;
  if (lane < 16) { m1 = pmax[(size_t)row * 80 + 64 + lane]; s1 = psum[(size_t)row * 80 + 64 + lane]; }
  float m = fmaxf(m0, m1);
  #pragma unroll
  for (int d = 1; d < 64; d <<= 1) m = fmaxf(m, __shfl_xor(m, d));
  float s = s0 * __expf(m0 - m) + s1 * __expf(m1 - m);
  #pragma unroll
  for (int d = 1; d < 64; d <<= 1) s += __shfl_xor(s, d);
  if (lane == 0) lse[row] = m + __logf(s);
}

// ---------------- gather raw label logits, TRANSPOSED: lgT[b][j][t] ---------------
__global__ void k_gather(const float* __restrict__ enc, const float* __restrict__ W,
                         const float* __restrict__ bias, const int* __restrict__ y,
                         float* __restrict__ lgT) {
  int row0 = blockIdx.x * 4;
  int lane = threadIdx.x;
  int b = row0 / T_LEN;
  int t0 = row0 - b * T_LEN;
  float4 e0 = ((const float4*)(enc + (size_t)(row0 + 0) * 256))[lane];
  float4 e1 = ((const float4*)(enc + (size_t)(row0 + 1) * 256))[lane];
  float4 e2 = ((const float4*)(enc + (size_t)(row0 + 2) * 256))[lane];
  float4 e3 = ((const float4*)(enc + (size_t)(row0 + 3) * 256))[lane];
  for (int j = 0; j < 51; ++j) {
    int v = (j == 0) ? 0 : y[b * L_LAB + j - 1];
    float4 w = ((const float4*)(W + (size_t)v * 256))[lane];
    float p0 = e0.x * w.x + e0.y * w.y + e0.z * w.z + e0.w * w.w;
    float p1 = e1.x * w.x + e1.y * w.y + e1.z * w.z + e1.w * w.w;
    float p2 = e2.x * w.x + e2.y * w.y + e2.z * w.z + e2.w * w.w;
    float p3 = e3.x * w.x + e3.y * w.y + e3.z * w.z + e3.w * w.w;
    #pragma unroll
    for (int d = 1; d < 64; d <<= 1) {
      p0 += __shfl_xor(p0, d);
      p1 += __shfl_xor(p1, d);
      p2 += __shfl_xor(p2, d);
      p3 += __shfl_xor(p3, d);
    }
    if (lane == 0) {
      float bb = bias[v];
      float4 o = {p0 + bb, p1 + bb, p2 + bb, p3 + bb};
      *(float4*)(lgT + (size_t)(b * 64 + j) * T_PAD + t0) = o;
    }
  }
}

// ---------------- cross-lane shift-by-1 via DPP wave_shr:1 ------------------------
__device__ __forceinline__ float wave_shr1(float x, float fill) {
#if defined(__has_builtin)
#if __has_builtin(__builtin_amdgcn_update_dpp)
  int r = __builtin_amdgcn_update_dpp(__float_as_int(fill), __float_as_int(x),
                                      0x138 /*wave_shr:1*/, 0xf, 0xf, false);
  return __int_as_float(r);
#else
  return __shfl_up(x, 1);
#endif
#else
  return __shfl_up(x, 1);
#endif
}

// ---------------- CTC forward DP --------------------------------------------------
// One block (256 thr) per batch element. 4 waves stage lgT[b] (51x512 f32, scaled
// by log2e) into LDS with coalesced float4 loads; then wave 0 runs the serial DP
// out of LDS (base-2 domain) while waves 1-3 reduce sum_t lse[b,t].
__global__ __launch_bounds__(256) void k_dp(
    const float* __restrict__ lgT, const float* __restrict__ lse,
    const int* __restrict__ enc_lens, const int* __restrict__ y,
    const int* __restrict__ y_lens, float* __restrict__ out) {
  __shared__ float sA[51 * DP_STR];   // 105 KB
  __shared__ float sRed[4];
  const int b = blockIdx.x, tid = threadIdx.x;
  const int Tb = enc_lens[b], yl = y_lens[b];

  // ---- stage: 51 rows x 128 float4 (cols 0..511; 500..511 are unused filler) ----
  const float* g = lgT + (size_t)(b * 64) * T_PAD;
  #pragma unroll
  for (int k = 0; k < 26; ++k) {
    int idx = tid + k * 256;
    if (idx < 51 * 128) {
      int row = idx >> 7, c4 = (idx & 127) << 2;
      float4 v = *(const float4*)(g + (size_t)row * T_PAD + c4);
      float4 s = {v.x * LOG2E, v.y * LOG2E, v.z * LOG2E, v.w * LOG2E};
      *(float4*)(sA + row * DP_STR + c4) = s;
    }
  }
  __syncthreads();

  if (tid < 64) {
    const int i = tid;
    const int jj = (i + 1 < 50) ? (i + 1) : 50;      // clamp; lanes>=50 masked
    const float* bl = sA;                             // blank row (broadcast)
    const float* ow = sA + jj * DP_STR;               // own label row
    const bool v0 = (i <= 50), v1 = (i <= 49);
    const bool lane0 = (i == 0);
    const bool skip1 = (i >= 1 && i <= 49) && (y[b * L_LAB + i] != y[b * L_LAB + i - 1]);

    float4 A0 = *(const float4*)(bl + 0),  A1 = *(const float4*)(ow + 0);
    float4 B0 = *(const float4*)(bl + 4),  B1 = *(const float4*)(ow + 4);
    float4 C0 = *(const float4*)(bl + 8),  C1 = *(const float4*)(ow + 8);
    float4 D0 = *(const float4*)(bl + 12), D1 = *(const float4*)(ow + 12);
    const float4 n4 = {NEG, NEG, NEG, NEG};
    if (!v1) { A1 = n4; B1 = n4; C1 = n4; D1 = n4; }

    float a0 = lane0 ? A0.x : NEG;
    float a1 = lane0 ? A1.x : NEG;

    auto step = [&](float l0r, float l1) {
      float l0 = v0 ? l0r : NEG;
      float p1 = wave_shr1(a1, NEG);
      p1 = lane0 ? NEG : p1;
      float th = skip1 ? p1 : NEG;
      float m0 = fmaxf(a0, p1);
      float na0 = m0 + flog2(fexp2(a0 - m0) + fexp2(p1 - m0)) + l0;
      float m1 = fmaxf(fmaxf(a1, a0), th);
      float na1 = m1 + flog2(fexp2(a1 - m1) + fexp2(a0 - m1) + fexp2(th - m1)) + l1;
      a0 = na0; a1 = na1;
    };

    step(A0.y, A1.y);
    step(A0.z, A1.z);
    step(A0.w, A1.w);

    float4 c0 = B0, c1 = B1, n0 = C0, n1 = C1, nn0 = D0, nn1 = D1;
    int t = 4;
    while (t + 4 <= Tb) {
      float4 p0 = *(const float4*)(bl + t + 12);   // max 508..511 < 512
      float4 p1v = *(const float4*)(ow + t + 12);
      if (!v1) p1v = n4;
      step(c0.x, c1.x);
      step(c0.y, c1.y);
      step(c0.z, c1.z);
      step(c0.w, c1.w);
      c0 = n0; c1 = n1; n0 = nn0; n1 = nn1; nn0 = p0; nn1 = p1v;
      t += 4;
    }
    if (t < Tb) { step(c0.x, c1.x); ++t; }
    if (t < Tb) { step(c0.y, c1.y); ++t; }
    if (t < Tb) { step(c0.z, c1.z); ++t; }

    float ea = __shfl(a0, yl);       // s = 2*yl
    float eb = __shfl(a1, yl - 1);   // s = 2*yl-1
    if (lane0) {
      float m = fmaxf(ea, eb);
      float fin2 = m + flog2(fexp2(ea - m) + fexp2(eb - m));
      sRed[0] = LN2 * fin2;          // back to natural log
    }
  } else {
    const int i = tid - 64;
    float sl = 0.f;
    for (int t = i; t < Tb; t += 192) sl += lse[b * T_LEN + t];
    #pragma unroll
    for (int d = 1; d < 64; d <<= 1) sl += __shfl_xor(sl, d);
    if ((tid & 63) == 0) sRed[tid >> 6] = sl;   // slots 1..3
  }
  __syncthreads();
  if (tid == 0) {
    float sl = sRed[1] + sRed[2] + sRed[3];
    atomicAdd(out, (sl - sRed[0]) * (1.0f / (float)B_SZ));
  }
}

extern "C" void kernel_launch(void* const* d_in, const int* in_sizes, int n_in,
                              void* d_out, int out_size, void* d_ws, size_t ws_size,
                              hipStream_t stream) {
  (void)in_sizes; (void)n_in; (void)out_size; (void)ws_size;
  const float* enc      = (const float*)d_in[0];   // [16][500][256]
  const int*   enc_lens = (const int*)d_in[1];     // [16]
  const int*   y        = (const int*)d_in[2];     // [16][50]
  const int*   y_lens   = (const int*)d_in[3];     // [16]
  const float* W        = (const float*)d_in[4];   // [5000][256]
  const float* bias     = (const float*)d_in[5];   // [5000]
  float* out = (float*)d_out;

  char* ws = (char*)d_ws;
  _Float16* ench = (_Float16*)(ws + 0);            // 4,096,000 B
  _Float16* wh   = (_Float16*)(ws + 4096000);      // 2,560,000 B
  float* pmax    = (float*)(ws + 6656000);         // 2,560,000 B
  float* psum    = (float*)(ws + 9216000);         // 2,560,000 B
  float* lse     = (float*)(ws + 11776000);        //    32,000 B
  // lgT [16][64][512] f32 = 2,097,152 B — aliases ench (consumed by k_gemm_lse,
  // which is stream-ordered before k_gather writes it).
  float* lgT     = (float*)(ws + 0);

  k_f2h<<<(512000 + 255) / 256, 256, 0, stream>>>(enc, ench, 512000, out);
  k_f2h<<<(320000 + 255) / 256, 256, 0, stream>>>(W, wh, 320000, nullptr);
  k_gemm_lse<<<dim3(40, 63), 256, 0, stream>>>(ench, wh, bias, pmax, psum);
  k_gather<<<2000, 64, 0, stream>>>(enc, W, bias, y, lgT);   // overwrites ench region
  k_lse<<<8000, 64, 0, stream>>>(pmax, psum, lse);
  k_dp<<<16, 256, 0, stream>>>(lgT, lse, enc_lens, y, y_lens, out);
}